// Round 4
// baseline (445.495 us; speedup 1.0000x reference)
//
#include <hip/hip_runtime.h>
#include <hip/hip_bf16.h>
#include <stdint.h>

typedef __bf16 bf16_t;
typedef __bf16 bf16x4 __attribute__((ext_vector_type(4)));
typedef __bf16 bf16x8 __attribute__((ext_vector_type(8)));
typedef float f32x4 __attribute__((ext_vector_type(4)));

#define MFMA_16x16x32(A, B, C) __builtin_amdgcn_mfma_f32_16x16x32_bf16(A, B, C, 0, 0, 0)

static constexpr float kScale = 0.08838834764831845f;  // 1/sqrt(128)
static constexpr float kLog2e = 1.4426950408889634f;
static constexpr float kC1 = kScale * kLog2e;  // raw-score -> exp2 argument

// async global->LDS, 16B per lane; LDS dst is wave-uniform base + lane*16
__device__ __forceinline__ void lds_cp16(void* lds, const void* g) {
  __builtin_amdgcn_global_load_lds(
      (__attribute__((address_space(1))) void*)(uintptr_t)g,
      (__attribute__((address_space(3))) void*)(uintptr_t)lds, 16, 0, 0);
}

// Stage a [R rows x K cols] bf16 tile into chunked LDS: (r,k) -> (k>>5)*(R*32)+r*32+(k&31).
template <int R, int K>
__device__ __forceinline__ void stage_tile(bf16_t* lds, const bf16_t* g, int ldg, int tid) {
  constexpr int TOT = R * K;
  constexpr int CH = R * 32;
  constexpr int ITERS = TOT / 2048;  // 256 threads * 8 elems
  const int wave = tid >> 6;
#pragma unroll
  for (int i = 0; i < ITERS; ++i) {
    int linear = i * 2048 + tid * 8;
    int chunk = linear / CH;
    int rem = linear % CH;
    int r = rem >> 5;
    int c = rem & 31;
    lds_cp16(lds + i * 2048 + wave * 512, g + r * ldg + chunk * 32 + c);
  }
}

__device__ __forceinline__ bf16x8 frag_ld(const bf16_t* lds_chunk, int row, int lane) {
  return *(const bf16x8*)(lds_chunk + row * 32 + ((lane >> 4) << 3));
}

// ---------- elementwise f32 -> bf16 convert ----------
__global__ void cvt_kernel(const float* __restrict__ src, bf16_t* __restrict__ dst) {
  const int i = (blockIdx.x * 256 + threadIdx.x) * 4;
  float4 v = *(const float4*)&src[i];
  bf16x4 o;
  o[0] = (bf16_t)v.x;
  o[1] = (bf16_t)v.y;
  o[2] = (bf16_t)v.z;
  o[3] = (bf16_t)v.w;
  *(bf16x4*)&dst[i] = o;
}

// ---------- tiled transpose f32 src -> bf16 dst: src[mats][R][C] -> dst[mats][C][R] ----------
__global__ void transpose_f32_k(const float* __restrict__ src, bf16_t* __restrict__ dst, int R,
                                int C) {
  __shared__ alignas(16) bf16_t tile[64][72];
  const int t = threadIdx.x;
  const int mat = blockIdx.z;
  const int r0 = blockIdx.x * 64, c0 = blockIdx.y * 64;
  const float* s = src + (size_t)mat * R * C;
  bf16_t* d = dst + (size_t)mat * R * C;
  const int rl = t >> 3, cl = (t & 7) * 8;
#pragma unroll
  for (int half = 0; half < 2; ++half) {
    const int r = r0 + rl + half * 32;
    float4 a = *(const float4*)&s[(size_t)r * C + c0 + cl];
    float4 b = *(const float4*)&s[(size_t)r * C + c0 + cl + 4];
    tile[cl + 0][rl + half * 32] = (bf16_t)a.x;
    tile[cl + 1][rl + half * 32] = (bf16_t)a.y;
    tile[cl + 2][rl + half * 32] = (bf16_t)a.z;
    tile[cl + 3][rl + half * 32] = (bf16_t)a.w;
    tile[cl + 4][rl + half * 32] = (bf16_t)b.x;
    tile[cl + 5][rl + half * 32] = (bf16_t)b.y;
    tile[cl + 6][rl + half * 32] = (bf16_t)b.z;
    tile[cl + 7][rl + half * 32] = (bf16_t)b.w;
  }
  __syncthreads();
  const int cl2 = t >> 3, rl2 = (t & 7) * 8;
  *(bf16x8*)&d[(size_t)(c0 + cl2) * R + r0 + rl2] = *(const bf16x8*)&tile[cl2][rl2];
  *(bf16x8*)&d[(size_t)(c0 + cl2 + 32) * R + r0 + rl2] = *(const bf16x8*)&tile[cl2 + 32][rl2];
}

// ---------- tiled bf16 transpose: src[mats][R][C] -> dst[mats][C][R] ----------
__global__ void transpose_k(const bf16_t* __restrict__ src, bf16_t* __restrict__ dst, int R,
                            int C) {
  __shared__ alignas(16) bf16_t tile[64][72];
  const int t = threadIdx.x;
  const int mat = blockIdx.z;
  const int r0 = blockIdx.x * 64, c0 = blockIdx.y * 64;
  const bf16_t* s = src + (size_t)mat * R * C;
  bf16_t* d = dst + (size_t)mat * R * C;
  const int rl = t >> 3, cl = (t & 7) * 8;
  bf16x8 v0 = *(const bf16x8*)&s[(size_t)(r0 + rl) * C + c0 + cl];
  bf16x8 v1 = *(const bf16x8*)&s[(size_t)(r0 + rl + 32) * C + c0 + cl];
#pragma unroll
  for (int j = 0; j < 8; ++j) {
    tile[cl + j][rl] = v0[j];
    tile[cl + j][rl + 32] = v1[j];
  }
  __syncthreads();
  const int cl2 = t >> 3, rl2 = (t & 7) * 8;
  *(bf16x8*)&d[(size_t)(c0 + cl2) * R + r0 + rl2] = *(const bf16x8*)&tile[cl2][rl2];
  *(bf16x8*)&d[(size_t)(c0 + cl2 + 32) * R + r0 + rl2] = *(const bf16x8*)&tile[cl2 + 32][rl2];
}

// ---------- projections ----------
// elem offsets: q mats 0..7 -> 0..4M ; k mats 8..15 -> 4..8M ; v mats 16..23 -> 12..16M
__global__ __launch_bounds__(256, 2) void proj_kernel(const bf16_t* __restrict__ X,
                                                      const bf16_t* __restrict__ Wt,
                                                      const float* __restrict__ bq,
                                                      const float* __restrict__ bk,
                                                      const float* __restrict__ bv,
                                                      bf16_t* __restrict__ qkv) {
  __shared__ alignas(16) bf16_t As[128 * 32];
  __shared__ alignas(16) bf16_t Bs[128 * 32];
  const int t = threadIdx.x, lane = t & 63, w = t >> 6;
  const int l15 = lane & 15, quad = lane >> 4;
  const int ntile = blockIdx.x, mat = blockIdx.y;
  const bf16_t* a0 = X + (size_t)ntile * 128 * 1024;
  const bf16_t* b0 = Wt + (size_t)mat * 131072;
  f32x4 acc[4][4] = {};
  const int rb = (w >> 1) * 64, cb = (w & 1) * 64;
  for (int k0 = 0; k0 < 1024; k0 += 32) {
    stage_tile<128, 32>(As, a0 + k0, 1024, t);
    stage_tile<128, 32>(Bs, b0 + k0, 1024, t);
    __syncthreads();
    bf16x8 af[4], bfr[4];
#pragma unroll
    for (int i = 0; i < 4; ++i) af[i] = frag_ld(As, rb + i * 16 + l15, lane);
#pragma unroll
    for (int j = 0; j < 4; ++j) bfr[j] = frag_ld(Bs, cb + j * 16 + l15, lane);
#pragma unroll
    for (int i = 0; i < 4; ++i)
#pragma unroll
      for (int j = 0; j < 4; ++j) acc[i][j] = MFMA_16x16x32(af[i], bfr[j], acc[i][j]);
    __syncthreads();
  }
  const int proj = mat >> 3, h = mat & 7;
  const float* bias = (proj == 0 ? bq : proj == 1 ? bk : bv) + h * 128;
  const size_t moff = (size_t)mat * 524288 + (mat >= 16 ? 4194304 : 0);
  bf16_t* outp = qkv + moff;
#pragma unroll
  for (int i = 0; i < 4; ++i) {
#pragma unroll
    for (int j = 0; j < 4; ++j) {
      const int e = cb + j * 16 + l15;
      const float bval = bias[e];
#pragma unroll
      for (int r = 0; r < 4; ++r) {
        const int n = ntile * 128 + rb + i * 16 + quad * 4 + r;
        outp[(size_t)n * 128 + e] = (bf16_t)(acc[i][j][r] + bval);
      }
    }
  }
}

// ---------- pass A: l2c[h][m] = log2( sum_n exp2(c1 * q[n].k[m]) ) ----------
// grid (64 mtile, 8 h). Barrier-free main loop: k frags resident (64 VGPR), q streamed
// directly global->VGPR (per-lane 16B fragment loads, no LDS, no __syncthreads).
__global__ __launch_bounds__(256, 4) void pass_a_kernel(const bf16_t* __restrict__ q,
                                                        const bf16_t* __restrict__ k,
                                                        float* __restrict__ l2c) {
  __shared__ alignas(16) float csred[4][64];
  const int t = threadIdx.x, lane = t & 63, w = t >> 6;
  const int quad = lane >> 4, l15 = lane & 15;
  const int mtile = blockIdx.x, h = blockIdx.y;
  const bf16_t* kb = k + ((size_t)h * 4096 + mtile * 64) * 128;
  const bf16_t* qb = q + (size_t)h * 4096 * 128;
  bf16x8 kf[4][4];  // B-operand: col m = mg*16+l15, kdim = ks*32+quad*8
#pragma unroll
  for (int mg = 0; mg < 4; ++mg)
#pragma unroll
    for (int ks = 0; ks < 4; ++ks)
      kf[mg][ks] = *(const bf16x8*)&kb[(mg * 16 + l15) * 128 + ks * 32 + quad * 8];
  float cs[4] = {0.f, 0.f, 0.f, 0.f};
  int n0 = w * 16;
  bf16x8 af[4];  // A-operand: row n = l15, kdim = ks*32+quad*8
#pragma unroll
  for (int ks = 0; ks < 4; ++ks)
    af[ks] = *(const bf16x8*)&qb[(size_t)(n0 + l15) * 128 + ks * 32 + quad * 8];
#pragma unroll 2
  for (int it = 0; it < 64; ++it) {
    const int n0n = (n0 + 64) & 4095;  // wrapped prefetch (last iter loads row 0 harmlessly)
    bf16x8 afn[4];
#pragma unroll
    for (int ks = 0; ks < 4; ++ks)
      afn[ks] = *(const bf16x8*)&qb[(size_t)(n0n + l15) * 128 + ks * 32 + quad * 8];
#pragma unroll
    for (int mg = 0; mg < 4; ++mg) {
      f32x4 c = {0.f, 0.f, 0.f, 0.f};
#pragma unroll
      for (int ks = 0; ks < 4; ++ks) c = MFMA_16x16x32(af[ks], kf[mg][ks], c);
#pragma unroll
      for (int r = 0; r < 4; ++r) cs[mg] += __builtin_exp2f(c[r] * kC1);
    }
#pragma unroll
    for (int ks = 0; ks < 4; ++ks) af[ks] = afn[ks];
    n0 += 64;
  }
#pragma unroll
  for (int mg = 0; mg < 4; ++mg) {
    cs[mg] += __shfl_xor(cs[mg], 16, 64);
    cs[mg] += __shfl_xor(cs[mg], 32, 64);
  }
  if (lane < 16) {
#pragma unroll
    for (int mg = 0; mg < 4; ++mg) csred[w][mg * 16 + lane] = cs[mg];
  }
  __syncthreads();
  if (t < 64)
    l2c[(size_t)h * 4096 + mtile * 64 + t] =
        __builtin_log2f(csred[0][t] + csred[1][t] + csred[2][t] + csred[3][t]);
}

// ---------- pass B: z[n][e] = sum_m exp2(c1*s - l2c[m]) * v[m][e]; sigmoid; store f32 ----------
// grid (64 ntile, 8 h). Barrier-free main loop: waves split n 2-way (npar) and interleave
// 32m strips 2-way (mpar). All operands loaded global->VGPR per-lane; LDS only for the
// same-wave P bounce (C-layout -> A-layout) and the epilogue mpar reduction.
__global__ __launch_bounds__(256, 2) void pass_b_kernel(const bf16_t* __restrict__ q,
                                                        const bf16_t* __restrict__ k,
                                                        const bf16_t* __restrict__ vT,
                                                        const float* __restrict__ l2c,
                                                        float* __restrict__ out) {
  __shared__ alignas(16) bf16_t sW_all[4][32][40];  // per-wave P bounce, pad 40 (10.25 KB)
  __shared__ alignas(16) float zred[2][4096];       // epilogue reduction (32 KB)
  const int t = threadIdx.x, lane = t & 63, w = t >> 6;
  const int quad = lane >> 4, l15 = lane & 15;
  const int npar = w & 1, mpar = w >> 1;
  const int ntile = blockIdx.x, h = blockIdx.y;
  const bf16_t* qb = q + ((size_t)h * 4096 + ntile * 64) * 128;
  const bf16_t* kb = k + (size_t)h * 4096 * 128;
  const bf16_t* vb = vT + (size_t)h * 128 * 4096;
  const float* lb = l2c + (size_t)h * 4096;
  // q B-operand fragments (col n), resident
  bf16x8 qf[2][4];
#pragma unroll
  for (int nsub = 0; nsub < 2; ++nsub)
#pragma unroll
    for (int ks = 0; ks < 4; ++ks)
      qf[nsub][ks] = *(const bf16x8*)&qb[(npar * 32 + nsub * 16 + l15) * 128 + ks * 32 + quad * 8];
  bf16_t* sW = &sW_all[w][0][0];
  f32x4 zacc[2][8] = {};
  int m0 = mpar * 32;
  bf16x8 kf[2][4];  // A-operand: row m = ms*16+l15, kdim = ks*32+quad*8
#pragma unroll
  for (int ms = 0; ms < 2; ++ms)
#pragma unroll
    for (int ks = 0; ks < 4; ++ks)
      kf[ms][ks] = *(const bf16x8*)&kb[(size_t)(m0 + ms * 16 + l15) * 128 + ks * 32 + quad * 8];
#pragma unroll 2
  for (int it = 0; it < 64; ++it) {
    const int m0n = (m0 + 64) & 4095;  // wrapped prefetch
    // l2c in C-layout rows (m = quad*4+r) — direct per-lane f32x4 loads
    f32x4 g0 = *(const f32x4*)&lb[m0 + quad * 4];
    f32x4 g1 = *(const f32x4*)&lb[m0 + 16 + quad * 4];
    // v B-operand fragments: col e = es*16+l15, kdim m = quad*8
    bf16x8 vf[8];
#pragma unroll
    for (int es = 0; es < 8; ++es)
      vf[es] = *(const bf16x8*)&vb[(size_t)(es * 16 + l15) * 4096 + m0 + quad * 8];
    // S^T[m(32)][n(32)]
    f32x4 cc[2][2] = {};
#pragma unroll
    for (int ks = 0; ks < 4; ++ks)
#pragma unroll
      for (int ms = 0; ms < 2; ++ms)
#pragma unroll
        for (int nsub = 0; nsub < 2; ++nsub)
          cc[ms][nsub] = MFMA_16x16x32(kf[ms][ks], qf[nsub][ks], cc[ms][nsub]);
    // prefetch next k fragments while exp2/PV run
    bf16x8 kfn[2][4];
#pragma unroll
    for (int ms = 0; ms < 2; ++ms)
#pragma unroll
      for (int ks = 0; ks < 4; ++ks)
        kfn[ms][ks] =
            *(const bf16x8*)&kb[(size_t)(m0n + ms * 16 + l15) * 128 + ks * 32 + quad * 8];
    // exp2 in C-layout, pack bf16, bounce through per-wave LDS (same-wave, in-order DS)
#pragma unroll
    for (int ms = 0; ms < 2; ++ms) {
      const f32x4 g = ms ? g1 : g0;
#pragma unroll
      for (int nsub = 0; nsub < 2; ++nsub) {
        bf16x4 pv;
#pragma unroll
        for (int r = 0; r < 4; ++r)
          pv[r] = (bf16_t)__builtin_exp2f(cc[ms][nsub][r] * kC1 - g[r]);
        *(bf16x4*)&sW[(nsub * 16 + l15) * 40 + ms * 16 + quad * 4] = pv;
      }
    }
    bf16x8 pf[2];  // P A-fragments: row n = l15, kdim m = quad*8
#pragma unroll
    for (int nsub = 0; nsub < 2; ++nsub)
      pf[nsub] = *(const bf16x8*)&sW[(nsub * 16 + l15) * 40 + quad * 8];
#pragma unroll
    for (int es = 0; es < 8; ++es)
#pragma unroll
      for (int nsub = 0; nsub < 2; ++nsub)
        zacc[nsub][es] = MFMA_16x16x32(pf[nsub], vf[es], zacc[nsub][es]);
#pragma unroll
    for (int ms = 0; ms < 2; ++ms)
#pragma unroll
      for (int ks = 0; ks < 4; ++ks) kf[ms][ks] = kfn[ms][ks];
    m0 += 64;
  }
  // epilogue: merge mpar pairs via LDS, sigmoid, store f32
  __syncthreads();
  if (mpar == 1) {
    float* dst = &zred[npar][0];
#pragma unroll
    for (int i = 0; i < 16; ++i) *(f32x4*)&dst[i * 256 + lane * 4] = zacc[i >> 3][i & 7];
  }
  __syncthreads();
  if (mpar == 0) {
    const float* src = &zred[npar][0];
#pragma unroll
    for (int nsub = 0; nsub < 2; ++nsub) {
#pragma unroll
      for (int es = 0; es < 8; ++es) {
        f32x4 o = *(const f32x4*)&src[(nsub * 8 + es) * 256 + lane * 4];
        const int e = es * 16 + l15;
#pragma unroll
        for (int r = 0; r < 4; ++r) {
          const int n = ntile * 64 + npar * 32 + nsub * 16 + quad * 4 + r;
          const float z = zacc[nsub][es][r] + o[r];
          out[(size_t)n * 1024 + h * 128 + e] = 1.f / (1.f + __builtin_exp2f(-z * kLog2e));
        }
      }
    }
  }
}

extern "C" void kernel_launch(void* const* d_in, const int* in_sizes, int n_in, void* d_out,
                              int out_size, void* d_ws, size_t ws_size, hipStream_t stream) {
  (void)in_sizes;
  (void)n_in;
  (void)out_size;
  (void)ws_size;
  const float* X = (const float*)d_in[0];
  const float* Wq = (const float*)d_in[1];
  const float* bq = (const float*)d_in[2];
  const float* Wk = (const float*)d_in[3];
  const float* bk = (const float*)d_in[4];
  const float* Wv = (const float*)d_in[5];
  const float* bv = (const float*)d_in[6];
  float* out = (float*)d_out;
  char* ws = (char*)d_ws;
  // layout (bytes):
  //  0        - 8388608 : q
  //  8388608  - 16777216: k
  //  16777216 - 25165824: Xb (cvt out, proj in) -> vTp (after proj)
  //  25165824 - 33554432: v (proj out; dead after v-transpose)
  //  33554432 - 39845888: Wt (dead after proj)
  //  39845888 - 39976960: l2c
  bf16_t* qp = (bf16_t*)(ws);
  bf16_t* kp = (bf16_t*)(ws + 8388608);
  bf16_t* Xb = (bf16_t*)(ws + 16777216);
  bf16_t* vTp = (bf16_t*)(ws + 16777216);
  bf16_t* vp = (bf16_t*)(ws + 25165824);
  bf16_t* Wt = (bf16_t*)(ws + 33554432);
  float* l2c = (float*)(ws + 39845888);

  cvt_kernel<<<4096, 256, 0, stream>>>(X, Xb);
  transpose_f32_k<<<dim3(16, 2, 8), 256, 0, stream>>>(Wq, Wt + (size_t)0 * 8 * 131072, 1024, 128);
  transpose_f32_k<<<dim3(16, 2, 8), 256, 0, stream>>>(Wk, Wt + (size_t)1 * 8 * 131072, 1024, 128);
  transpose_f32_k<<<dim3(16, 2, 8), 256, 0, stream>>>(Wv, Wt + (size_t)2 * 8 * 131072, 1024, 128);
  proj_kernel<<<dim3(32, 24), 256, 0, stream>>>(Xb, Wt, bq, bk, bv, qp);
  transpose_k<<<dim3(64, 2, 8), 256, 0, stream>>>(vp, vTp, 4096, 128);
  pass_a_kernel<<<dim3(64, 8), 256, 0, stream>>>(qp, kp, l2c);
  pass_b_kernel<<<dim3(64, 8), 256, 0, stream>>>(qp, kp, vTp, l2c, out);
}

// Round 5
// 280.363 us; speedup vs baseline: 1.5890x; 1.5890x over previous
//
#include <hip/hip_runtime.h>
#include <hip/hip_bf16.h>
#include <stdint.h>

typedef __bf16 bf16_t;
typedef __bf16 bf16x4 __attribute__((ext_vector_type(4)));
typedef __bf16 bf16x8 __attribute__((ext_vector_type(8)));
typedef float f32x4 __attribute__((ext_vector_type(4)));

#define MFMA_16x16x32(A, B, C) __builtin_amdgcn_mfma_f32_16x16x32_bf16(A, B, C, 0, 0, 0)
#define EXP2(x) __builtin_amdgcn_exp2f(x)

static constexpr float kScale = 0.08838834764831845f;  // 1/sqrt(128)
static constexpr float kLog2e = 1.4426950408889634f;
static constexpr float kC1 = kScale * kLog2e;  // raw-score -> exp2 argument

// async global->LDS, 16B per lane; LDS dst is wave-uniform base + lane*16
__device__ __forceinline__ void lds_cp16(void* lds, const void* g) {
  __builtin_amdgcn_global_load_lds(
      (__attribute__((address_space(1))) void*)(uintptr_t)g,
      (__attribute__((address_space(3))) void*)(uintptr_t)lds, 16, 0, 0);
}

// Stage a [R rows x K cols] bf16 tile into chunked LDS: (r,k) -> (k>>5)*(R*32)+r*32+(k&31).
template <int R, int K>
__device__ __forceinline__ void stage_tile(bf16_t* lds, const bf16_t* g, int ldg, int tid) {
  constexpr int TOT = R * K;
  constexpr int CH = R * 32;
  constexpr int ITERS = TOT / 2048;  // 256 threads * 8 elems
  const int wave = tid >> 6;
#pragma unroll
  for (int i = 0; i < ITERS; ++i) {
    int linear = i * 2048 + tid * 8;
    int chunk = linear / CH;
    int rem = linear % CH;
    int r = rem >> 5;
    int c = rem & 31;
    lds_cp16(lds + i * 2048 + wave * 512, g + r * ldg + chunk * 32 + c);
  }
}

__device__ __forceinline__ bf16x8 frag_ld(const bf16_t* lds_chunk, int row, int lane) {
  return *(const bf16x8*)(lds_chunk + row * 32 + ((lane >> 4) << 3));
}

// ---------- elementwise f32 -> bf16 convert ----------
__global__ void cvt_kernel(const float* __restrict__ src, bf16_t* __restrict__ dst) {
  const int i = (blockIdx.x * 256 + threadIdx.x) * 4;
  float4 v = *(const float4*)&src[i];
  bf16x4 o;
  o[0] = (bf16_t)v.x;
  o[1] = (bf16_t)v.y;
  o[2] = (bf16_t)v.z;
  o[3] = (bf16_t)v.w;
  *(bf16x4*)&dst[i] = o;
}

// ---------- tiled transpose f32 src -> bf16 dst: src[mats][R][C] -> dst[mats][C][R] ----------
__global__ void transpose_f32_k(const float* __restrict__ src, bf16_t* __restrict__ dst, int R,
                                int C) {
  __shared__ alignas(16) bf16_t tile[64][72];
  const int t = threadIdx.x;
  const int mat = blockIdx.z;
  const int r0 = blockIdx.x * 64, c0 = blockIdx.y * 64;
  const float* s = src + (size_t)mat * R * C;
  bf16_t* d = dst + (size_t)mat * R * C;
  const int rl = t >> 3, cl = (t & 7) * 8;
#pragma unroll
  for (int half = 0; half < 2; ++half) {
    const int r = r0 + rl + half * 32;
    float4 a = *(const float4*)&s[(size_t)r * C + c0 + cl];
    float4 b = *(const float4*)&s[(size_t)r * C + c0 + cl + 4];
    tile[cl + 0][rl + half * 32] = (bf16_t)a.x;
    tile[cl + 1][rl + half * 32] = (bf16_t)a.y;
    tile[cl + 2][rl + half * 32] = (bf16_t)a.z;
    tile[cl + 3][rl + half * 32] = (bf16_t)a.w;
    tile[cl + 4][rl + half * 32] = (bf16_t)b.x;
    tile[cl + 5][rl + half * 32] = (bf16_t)b.y;
    tile[cl + 6][rl + half * 32] = (bf16_t)b.z;
    tile[cl + 7][rl + half * 32] = (bf16_t)b.w;
  }
  __syncthreads();
  const int cl2 = t >> 3, rl2 = (t & 7) * 8;
  *(bf16x8*)&d[(size_t)(c0 + cl2) * R + r0 + rl2] = *(const bf16x8*)&tile[cl2][rl2];
  *(bf16x8*)&d[(size_t)(c0 + cl2 + 32) * R + r0 + rl2] = *(const bf16x8*)&tile[cl2 + 32][rl2];
}

// ---------- projections ----------
// elem offsets: q mats 0..7 -> 0..4M ; k mats 8..15 -> 4..8M ; v mats 16..23 -> 12..16M
__global__ __launch_bounds__(256, 2) void proj_kernel(const bf16_t* __restrict__ X,
                                                      const bf16_t* __restrict__ Wt,
                                                      const float* __restrict__ bq,
                                                      const float* __restrict__ bk,
                                                      const float* __restrict__ bv,
                                                      bf16_t* __restrict__ qkv) {
  __shared__ alignas(16) bf16_t As[128 * 32];
  __shared__ alignas(16) bf16_t Bs[128 * 32];
  const int t = threadIdx.x, lane = t & 63, w = t >> 6;
  const int l15 = lane & 15, quad = lane >> 4;
  const int ntile = blockIdx.x, mat = blockIdx.y;
  const bf16_t* a0 = X + (size_t)ntile * 128 * 1024;
  const bf16_t* b0 = Wt + (size_t)mat * 131072;
  f32x4 acc[4][4] = {};
  const int rb = (w >> 1) * 64, cb = (w & 1) * 64;
  for (int k0 = 0; k0 < 1024; k0 += 32) {
    stage_tile<128, 32>(As, a0 + k0, 1024, t);
    stage_tile<128, 32>(Bs, b0 + k0, 1024, t);
    __syncthreads();
    bf16x8 af[4], bfr[4];
#pragma unroll
    for (int i = 0; i < 4; ++i) af[i] = frag_ld(As, rb + i * 16 + l15, lane);
#pragma unroll
    for (int j = 0; j < 4; ++j) bfr[j] = frag_ld(Bs, cb + j * 16 + l15, lane);
#pragma unroll
    for (int i = 0; i < 4; ++i)
#pragma unroll
      for (int j = 0; j < 4; ++j) acc[i][j] = MFMA_16x16x32(af[i], bfr[j], acc[i][j]);
    __syncthreads();
  }
  const int proj = mat >> 3, h = mat & 7;
  const float* bias = (proj == 0 ? bq : proj == 1 ? bk : bv) + h * 128;
  const size_t moff = (size_t)mat * 524288 + (mat >= 16 ? 4194304 : 0);
  bf16_t* outp = qkv + moff;
#pragma unroll
  for (int i = 0; i < 4; ++i) {
#pragma unroll
    for (int j = 0; j < 4; ++j) {
      const int e = cb + j * 16 + l15;
      const float bval = bias[e];
#pragma unroll
      for (int r = 0; r < 4; ++r) {
        const int n = ntile * 128 + rb + i * 16 + quad * 4 + r;
        outp[(size_t)n * 128 + e] = (bf16_t)(acc[i][j][r] + bval);
      }
    }
  }
}

// ---------- repack q/k rows into fragment-major layout ----------
// src[h][4096][128] row-major -> F[h][nt(256)][ks(4)][lane(64)][8] ; frag = contiguous 1KB.
__global__ void repack_qk(const bf16_t* __restrict__ src, bf16_t* __restrict__ dst) {
  __shared__ alignas(16) bf16_t S[64 * 128];
  const int t = threadIdx.x, lane = t & 63, w = t >> 6, l15 = lane & 15;
  const int h = blockIdx.x, ng = blockIdx.y;
  const bf16_t* s = src + ((size_t)h * 4096 + ng * 64) * 128;
  stage_tile<64, 128>(S, s, 128, t);
  __syncthreads();
  const int nt = ng * 4 + w;
#pragma unroll
  for (int ks = 0; ks < 4; ++ks) {
    bf16x8 f = frag_ld(S + ks * 2048, w * 16 + l15, lane);
    *(bf16x8*)&dst[(((size_t)h * 256 + nt) * 4 + ks) * 512 + lane * 8] = f;
  }
}

// ---------- repack v into transposed fragment-major layout ----------
// v[h][4096 m][128 e] -> Vf[h][mb(128)][es(8)][lane(64)][8]
// lane holds v[mb*32 + quad*8 + j][es*16 + l15]  (B-operand frag for PV, k-dim = m)
__global__ void repack_v(const bf16_t* __restrict__ v, bf16_t* __restrict__ Vf) {
  __shared__ alignas(16) bf16_t tile[64][72];  // [e_local][m_local]
  const int t = threadIdx.x;
  const int h = blockIdx.z;
  const int r0 = blockIdx.x * 64, c0 = blockIdx.y * 64;  // m-block, e-block
  const bf16_t* s = v + (size_t)h * 4096 * 128;
  const int rl = t >> 3, cl = (t & 7) * 8;
  bf16x8 v0 = *(const bf16x8*)&s[(size_t)(r0 + rl) * 128 + c0 + cl];
  bf16x8 v1 = *(const bf16x8*)&s[(size_t)(r0 + rl + 32) * 128 + c0 + cl];
#pragma unroll
  for (int j = 0; j < 8; ++j) {
    tile[cl + j][rl] = v0[j];
    tile[cl + j][rl + 32] = v1[j];
  }
  __syncthreads();
  const int lane = t & 63, w = t >> 6, quad = lane >> 4, l15 = lane & 15;
  const int es = (c0 >> 4) + w;
#pragma unroll
  for (int mi = 0; mi < 2; ++mi) {
    bf16x8 f = *(const bf16x8*)&tile[w * 16 + l15][mi * 32 + quad * 8];
    const int mb = (r0 >> 5) + mi;
    *(bf16x8*)&Vf[(((size_t)h * 128 + mb) * 8 + es) * 512 + lane * 8] = f;
  }
}

// ---------- pass A: l2c[h][m] = log2( sum_n exp2(c1 * q[n].k[m]) ) ----------
// grid (8 h, 64 mtile); x = h so each XCD caches its own head's Qf. Barrier-free loop,
// all operand loads are contiguous 1KB wave loads from fragment-major layout.
__global__ __launch_bounds__(256, 3) void pass_a_kernel(const bf16_t* __restrict__ Qf,
                                                        const bf16_t* __restrict__ Kf,
                                                        float* __restrict__ l2c) {
  __shared__ alignas(16) float csred[4][64];
  const int t = threadIdx.x, lane = t & 63, w = t >> 6;
  const int h = blockIdx.x, mtile = blockIdx.y;
  const bf16_t* Qh = Qf + (size_t)h * 524288;
  const bf16_t* Kh = Kf + (size_t)h * 524288;
  bf16x8 kf[4][4];  // B-operand: col m = mg*16 + l15
#pragma unroll
  for (int mg = 0; mg < 4; ++mg)
#pragma unroll
    for (int ks = 0; ks < 4; ++ks)
      kf[mg][ks] = *(const bf16x8*)&Kh[((size_t)(mtile * 4 + mg) * 4 + ks) * 512 + lane * 8];
  float cs[4] = {0.f, 0.f, 0.f, 0.f};
  bf16x8 af[4];
#pragma unroll
  for (int ks = 0; ks < 4; ++ks)
    af[ks] = *(const bf16x8*)&Qh[(size_t)(w * 4 + ks) * 512 + lane * 8];
  for (int it = 0; it < 64; ++it) {
    const int ntn = ((it + 1) * 4 + w) & 255;  // wrapped prefetch
    bf16x8 afn[4];
#pragma unroll
    for (int ks = 0; ks < 4; ++ks)
      afn[ks] = *(const bf16x8*)&Qh[((size_t)ntn * 4 + ks) * 512 + lane * 8];
#pragma unroll
    for (int mg = 0; mg < 4; ++mg) {
      f32x4 c = {0.f, 0.f, 0.f, 0.f};
#pragma unroll
      for (int ks = 0; ks < 4; ++ks) c = MFMA_16x16x32(af[ks], kf[mg][ks], c);
#pragma unroll
      for (int r = 0; r < 4; ++r) cs[mg] += EXP2(c[r] * kC1);
    }
#pragma unroll
    for (int ks = 0; ks < 4; ++ks) af[ks] = afn[ks];
  }
#pragma unroll
  for (int mg = 0; mg < 4; ++mg) {
    cs[mg] += __shfl_xor(cs[mg], 16, 64);
    cs[mg] += __shfl_xor(cs[mg], 32, 64);
  }
  if (lane < 16) {
#pragma unroll
    for (int mg = 0; mg < 4; ++mg) csred[w][mg * 16 + lane] = cs[mg];
  }
  __syncthreads();
  if (t < 64)
    l2c[(size_t)h * 4096 + mtile * 64 + t] =
        __builtin_log2f(csred[0][t] + csred[1][t] + csred[2][t] + csred[3][t]);
}

// ---------- pass B: z[n][e] = sum_m exp2(c1*s - l2c[m]) * v[m][e]; sigmoid; store f32 ----------
// grid (8 h, 64 ntile); x = h -> each XCD streams one head's Kf/Vf (4MB, fits its L2).
// Waves: npar = w&1 (32n half), mpar = w>>1 (alternating 32m strips). Barrier-free loop:
// all operands contiguous 1KB wave loads; LDS only for same-wave P bounce + epilogue reduce.
__global__ __launch_bounds__(256, 2) void pass_b_kernel(const bf16_t* __restrict__ Qf,
                                                        const bf16_t* __restrict__ Kf,
                                                        const bf16_t* __restrict__ Vf,
                                                        const float* __restrict__ l2c,
                                                        float* __restrict__ out) {
  __shared__ alignas(16) bf16_t sW_all[4][32][40];  // per-wave P bounce (10.25 KB)
  __shared__ alignas(16) float zred[2][4096];       // epilogue reduction (32 KB)
  const int t = threadIdx.x, lane = t & 63, w = t >> 6;
  const int quad = lane >> 4, l15 = lane & 15;
  const int npar = w & 1, mpar = w >> 1;
  const int h = blockIdx.x, ntile = blockIdx.y;
  const bf16_t* Qh = Qf + (size_t)h * 524288;
  const bf16_t* Kh = Kf + (size_t)h * 524288;
  const bf16_t* Vh = Vf + (size_t)h * 524288;
  const float* lb = l2c + (size_t)h * 4096;
  // q B-operand fragments (col n = wave's 32n), resident
  bf16x8 qf[2][4];
#pragma unroll
  for (int nsub = 0; nsub < 2; ++nsub)
#pragma unroll
    for (int ks = 0; ks < 4; ++ks)
      qf[nsub][ks] = *(const bf16x8*)&Qh[((size_t)(ntile * 4 + npar * 2 + nsub) * 4 + ks) * 512 +
                                         lane * 8];
  bf16_t* sW = &sW_all[w][0][0];
  f32x4 zacc[2][8] = {};
  // preload k A-frags for first strip
  bf16x8 kf[2][4];
#pragma unroll
  for (int ms = 0; ms < 2; ++ms)
#pragma unroll
    for (int ks = 0; ks < 4; ++ks)
      kf[ms][ks] = *(const bf16x8*)&Kh[((size_t)(mpar * 2 + ms) * 4 + ks) * 512 + lane * 8];
  for (int it = 0; it < 64; ++it) {
    const int st = it * 2 + mpar;         // 32m strip id (0..127)
    const int stn = (st + 2) & 127;       // wrapped prefetch
    // issue v frags + l2c for current strip early (used at the end of the iter)
    bf16x8 vf[8];
#pragma unroll
    for (int es = 0; es < 8; ++es)
      vf[es] = *(const bf16x8*)&Vh[((size_t)st * 8 + es) * 512 + lane * 8];
    f32x4 g0 = *(const f32x4*)&lb[st * 32 + quad * 4];
    f32x4 g1 = *(const f32x4*)&lb[st * 32 + 16 + quad * 4];
    // QK^T: S^T tile [32m][32n]
    f32x4 cc[2][2] = {};
#pragma unroll
    for (int ks = 0; ks < 4; ++ks)
#pragma unroll
      for (int ms = 0; ms < 2; ++ms)
#pragma unroll
        for (int nsub = 0; nsub < 2; ++nsub)
          cc[ms][nsub] = MFMA_16x16x32(kf[ms][ks], qf[nsub][ks], cc[ms][nsub]);
    // prefetch next strip's k frags while exp2/PV run
    bf16x8 kfn[2][4];
#pragma unroll
    for (int ms = 0; ms < 2; ++ms)
#pragma unroll
      for (int ks = 0; ks < 4; ++ks)
        kfn[ms][ks] = *(const bf16x8*)&Kh[((size_t)(stn * 2 + ms) * 4 + ks) * 512 + lane * 8];
    // exp2 in C-layout (row m = ms*16+quad*4+r, col n = nsub*16+l15), bounce to A-layout
#pragma unroll
    for (int ms = 0; ms < 2; ++ms) {
      const f32x4 g = ms ? g1 : g0;
#pragma unroll
      for (int nsub = 0; nsub < 2; ++nsub) {
        bf16x4 pv;
#pragma unroll
        for (int r = 0; r < 4; ++r) pv[r] = (bf16_t)EXP2(cc[ms][nsub][r] * kC1 - g[r]);
        *(bf16x4*)&sW[(nsub * 16 + l15) * 40 + ms * 16 + quad * 4] = pv;
      }
    }
    bf16x8 pf[2];  // P A-frags: row n = l15, k m = quad*8+j (same-wave, in-order DS)
#pragma unroll
    for (int nsub = 0; nsub < 2; ++nsub)
      pf[nsub] = *(const bf16x8*)&sW[(nsub * 16 + l15) * 40 + quad * 8];
#pragma unroll
    for (int es = 0; es < 8; ++es)
#pragma unroll
      for (int nsub = 0; nsub < 2; ++nsub)
        zacc[nsub][es] = MFMA_16x16x32(pf[nsub], vf[es], zacc[nsub][es]);
#pragma unroll
    for (int ms = 0; ms < 2; ++ms)
#pragma unroll
      for (int ks = 0; ks < 4; ++ks) kf[ms][ks] = kfn[ms][ks];
  }
  // epilogue: merge mpar pairs via LDS, sigmoid, store f32
  __syncthreads();
  if (mpar == 1) {
    float* dst = &zred[npar][0];
#pragma unroll
    for (int i = 0; i < 16; ++i) *(f32x4*)&dst[i * 256 + lane * 4] = zacc[i >> 3][i & 7];
  }
  __syncthreads();
  if (mpar == 0) {
    const float* src = &zred[npar][0];
#pragma unroll
    for (int nsub = 0; nsub < 2; ++nsub) {
#pragma unroll
      for (int es = 0; es < 8; ++es) {
        f32x4 o = *(const f32x4*)&src[(nsub * 8 + es) * 256 + lane * 4];
        const int e = es * 16 + l15;
#pragma unroll
        for (int r = 0; r < 4; ++r) {
          const int n = ntile * 64 + npar * 32 + nsub * 16 + quad * 4 + r;
          const float z = zacc[nsub][es][r] + o[r];
          out[(size_t)n * 1024 + h * 128 + e] = 1.f / (1.f + EXP2(-z * kLog2e));
        }
      }
    }
  }
}

extern "C" void kernel_launch(void* const* d_in, const int* in_sizes, int n_in, void* d_out,
                              int out_size, void* d_ws, size_t ws_size, hipStream_t stream) {
  (void)in_sizes;
  (void)n_in;
  (void)out_size;
  (void)ws_size;
  const float* X = (const float*)d_in[0];
  const float* Wq = (const float*)d_in[1];
  const float* bq = (const float*)d_in[2];
  const float* Wk = (const float*)d_in[3];
  const float* bk = (const float*)d_in[4];
  const float* Wv = (const float*)d_in[5];
  const float* bv = (const float*)d_in[6];
  float* out = (float*)d_out;
  char* ws = (char*)d_ws;
  // byte layout with staged reuse (max 38.3 MB):
  //  [0,8M):    q_rm (proj out)         -> Kf   (after repack_k)
  //  [8M,16M):  k_rm (proj out)         -> l2c  (after repack_k)
  //  [16M,24M): Xb (cvt out, proj in)   -> Vf   (after repack_v)
  //  [24M,32M): v_rm (proj out)         -> Qf   (after repack_q)
  //  [32M,38.3M): Wt (dead after proj)
  bf16_t* q_rm = (bf16_t*)(ws);
  bf16_t* Kf = (bf16_t*)(ws);
  bf16_t* k_rm = (bf16_t*)(ws + 8388608);
  float* l2c = (float*)(ws + 8388608);
  bf16_t* Xb = (bf16_t*)(ws + 16777216);
  bf16_t* Vf = (bf16_t*)(ws + 16777216);
  bf16_t* v_rm = (bf16_t*)(ws + 25165824);
  bf16_t* Qf = (bf16_t*)(ws + 25165824);
  bf16_t* Wt = (bf16_t*)(ws + 33554432);

  cvt_kernel<<<4096, 256, 0, stream>>>(X, Xb);
  transpose_f32_k<<<dim3(16, 2, 8), 256, 0, stream>>>(Wq, Wt + (size_t)0 * 8 * 131072, 1024, 128);
  transpose_f32_k<<<dim3(16, 2, 8), 256, 0, stream>>>(Wk, Wt + (size_t)1 * 8 * 131072, 1024, 128);
  transpose_f32_k<<<dim3(16, 2, 8), 256, 0, stream>>>(Wv, Wt + (size_t)2 * 8 * 131072, 1024, 128);
  proj_kernel<<<dim3(32, 24), 256, 0, stream>>>(Xb, Wt, bq, bk, bv, q_rm);
  repack_v<<<dim3(64, 2, 8), 256, 0, stream>>>(v_rm, Vf);        // v_rm dead after
  repack_qk<<<dim3(8, 64), 256, 0, stream>>>(q_rm, Qf);          // q_rm dead after
  repack_qk<<<dim3(8, 64), 256, 0, stream>>>(k_rm, Kf);          // k_rm dead after
  pass_a_kernel<<<dim3(8, 64), 256, 0, stream>>>(Qf, Kf, l2c);
  pass_b_kernel<<<dim3(8, 64), 256, 0, stream>>>(Qf, Kf, Vf, l2c, out);
}